// Round 13
// baseline (527.122 us; speedup 1.0000x reference)
//
#include <hip/hip_runtime.h>
#include <hip/hip_bf16.h>
#include <math.h>

#define B_    8
#define T_    2560
#define F_    229
#define C1_   5
#define C2_   11
#define W1_   114
#define W2_   57
#define KP_   640
#define OF_   88
#define MC_   48
#define G_    8
#define DH_   6
#define K_    31
#define PAD_  15
#define BN_EPS 1e-5f
#define LN_EPS 1e-5f
#define TS_   8
#define TT_   16    // attn t-tile
#define FC_REP   3  // measurement: idempotent internal repeats
#define ATTN_REP 3

typedef __attribute__((ext_vector_type(8))) short short8;
typedef __attribute__((ext_vector_type(4))) float f32x4;

static inline int cdiv(int a, int b) { return (a + b - 1) / b; }

__device__ inline float bflo(unsigned u) { return __uint_as_float(u << 16); }
__device__ inline float bfhi(unsigned u) { return __uint_as_float(u & 0xffff0000u); }

// ---- fused conv1+conv2+pool+conv3+pool: spec (B,T,229) -> x3bf [bt][640] ----
__global__ __launch_bounds__(640, 8) void conv123_kernel(
        const float* __restrict__ spec,
        const float* __restrict__ c1w, const float* __restrict__ c1b,
        const float* __restrict__ g1, const float* __restrict__ b1,
        const float* __restrict__ m1, const float* __restrict__ v1,
        const float* __restrict__ c2w, const float* __restrict__ c2b,
        const float* __restrict__ g2, const float* __restrict__ b2,
        const float* __restrict__ m2, const float* __restrict__ v2,
        const float* __restrict__ c3w, const float* __restrict__ c3b,
        const float* __restrict__ g3, const float* __restrict__ b3,
        const float* __restrict__ m3, const float* __restrict__ v3,
        __hip_bfloat16* __restrict__ x3out) {
    __shared__ ushort x1t[12 * 5 * 232];     // 27,840 B bf16 (col = f+1)
    __shared__ float specx2[14 * 232];       // 12,992 B: spec tile, then x2p bf16 tile
    __shared__ float w1s[45], w2s[225], w3s[495];
    __shared__ float scl1[5], shf1[5], scl2[5], shf2[5], scl3[11], shf3[11];
    int t0 = blockIdx.x * TS_;
    int b = blockIdx.y;
    int tid = threadIdx.x;

    if (tid < 45) w1s[tid] = c1w[tid];
    for (int i = tid; i < 225; i += 640) w2s[i] = c2w[i];
    for (int i = tid; i < 495; i += 640) w3s[i] = c3w[i];
    if (tid < 5) {
        float s = g1[tid] * rsqrtf(v1[tid] + BN_EPS);
        scl1[tid] = s;
        shf1[tid] = (c1b[tid] - m1[tid]) * s + b1[tid];
    }
    if (tid >= 64 && tid < 69) {
        int c = tid - 64;
        float s = g2[c] * rsqrtf(v2[c] + BN_EPS);
        scl2[c] = s;
        shf2[c] = (c2b[c] - m2[c]) * s + b2[c];
    }
    if (tid >= 128 && tid < 139) {
        int c = tid - 128;
        float s = g3[c] * rsqrtf(v3[c] + BN_EPS);
        scl3[c] = s;
        shf3[c] = (c3b[c] - m3[c]) * s + b3[c];
    }
    {
        const float* sb = spec + (size_t)b * T_ * F_;
        for (int i = tid; i < 14 * 232; i += 640) {
            int col = i % 232;
            int rr = i / 232;
            int t = t0 - 3 + rr;
            int f = col - 1;
            float v = 0.f;
            if (t >= 0 && t < T_ && f >= 0 && f < F_) v = sb[(size_t)t * F_ + f];
            specx2[i] = v;
        }
    }
    __syncthreads();

    // ---- phase 1: conv1+bn+relu -> x1t rows t0-2..t0+9 (bf16) ----
    for (int i = tid; i < 12 * 229; i += 640) {
        int f = i % 229;
        int rr = i / 229;
        int t = t0 - 2 + rr;
        float y[5];
        if (t >= 0 && t < T_) {
            float tp[9];
#pragma unroll
            for (int dt = 0; dt < 3; ++dt) {
                const float* row = &specx2[(rr + dt) * 232 + f];
                tp[dt * 3 + 0] = row[0];
                tp[dt * 3 + 1] = row[1];
                tp[dt * 3 + 2] = row[2];
            }
#pragma unroll
            for (int co = 0; co < 5; ++co) {
                float acc = 0.f;
#pragma unroll
                for (int k = 0; k < 9; ++k) acc = fmaf(tp[k], w1s[co * 9 + k], acc);
                y[co] = fmaxf(fmaf(acc, scl1[co], shf1[co]), 0.f);
            }
        } else {
#pragma unroll
            for (int co = 0; co < 5; ++co) y[co] = 0.f;
        }
#pragma unroll
        for (int co = 0; co < 5; ++co) {
            __hip_bfloat16 h = __float2bfloat16(y[co]);
            x1t[(rr * 5 + co) * 232 + 1 + f] = *(ushort*)&h;
        }
    }
    for (int i = tid; i < 180; i += 640) {
        int c = i % 3;
        int col = (c == 0) ? 0 : 229 + c;
        int ci = (i / 3) % 5;
        int rr = i / 15;
        x1t[(rr * 5 + ci) * 232 + col] = 0;
    }
    __syncthreads();

    // ---- phase 2: conv2+bn+relu+pool -> x2pt (bf16, unions with spec tile) ----
    ushort* x2pt = (ushort*)specx2;
    if (tid < 570) {
        int co = tid / 114;
        int j = tid % 114;
        float acc0[10], acc1[10];
#pragma unroll
        for (int r = 0; r < 10; ++r) { acc0[r] = 0.f; acc1[r] = 0.f; }
#pragma unroll
        for (int ci = 0; ci < 5; ++ci) {
            float wr[9];
#pragma unroll
            for (int k = 0; k < 9; ++k) wr[k] = w2s[(co * 5 + ci) * 9 + k];
#pragma unroll
            for (int rr = 0; rr < 12; ++rr) {
                const ushort* p = &x1t[(rr * 5 + ci) * 232 + 2 * j];
                unsigned u0 = *(const unsigned*)p;
                unsigned u1 = *(const unsigned*)(p + 2);
                float v0 = bflo(u0), v1 = bfhi(u0), v2_ = bflo(u1), v3_ = bfhi(u1);
#pragma unroll
                for (int dt = 0; dt < 3; ++dt) {
                    int r = rr - dt;
                    if (r >= 0 && r < 10) {
                        acc0[r] = fmaf(v0, wr[dt * 3],
                                  fmaf(v1, wr[dt * 3 + 1],
                                  fmaf(v2_, wr[dt * 3 + 2], acc0[r])));
                        acc1[r] = fmaf(v1, wr[dt * 3],
                                  fmaf(v2_, wr[dt * 3 + 1],
                                  fmaf(v3_, wr[dt * 3 + 2], acc1[r])));
                    }
                }
            }
        }
        float s = scl2[co], sh = shf2[co];
        float yv[10];
#pragma unroll
        for (int r = 0; r < 10; ++r) {
            int t = t0 - 1 + r;
            float y = fmaxf(fmaxf(acc0[r] * s + sh, 0.f), fmaxf(acc1[r] * s + sh, 0.f));
            yv[r] = (t < 0 || t >= T_) ? 0.f : y;
        }
        __syncthreads();
#pragma unroll
        for (int r = 0; r < 10; ++r) {
            __hip_bfloat16 h = __float2bfloat16(yv[r]);
            x2pt[(r * 5 + co) * 120 + 1 + j] = *(ushort*)&h;
        }
    } else {
        __syncthreads();
        for (int i = tid - 570; i < 300; i += 70) {
            int cc = i % 6;
            int col = (cc == 0) ? 0 : 114 + cc;
            int ci = (i / 6) % 5;
            int r = i / 30;
            x2pt[(r * 5 + ci) * 120 + col] = 0;
        }
    }
    __syncthreads();

    // ---- phase 3: conv3+bn+relu+pool -> x3out bf16 [bt][640] ----
    if (tid < 627) {
        int co = tid / 57;
        int j = tid % 57;
        float acc0[8], acc1[8];
#pragma unroll
        for (int r = 0; r < 8; ++r) { acc0[r] = 0.f; acc1[r] = 0.f; }
#pragma unroll
        for (int ci = 0; ci < 5; ++ci) {
            float wr[9];
#pragma unroll
            for (int k = 0; k < 9; ++k) wr[k] = w3s[(co * 5 + ci) * 9 + k];
#pragma unroll
            for (int rr = 0; rr < 10; ++rr) {
                const ushort* p = &x2pt[(rr * 5 + ci) * 120 + 2 * j];
                unsigned u0 = *(const unsigned*)p;
                unsigned u1 = *(const unsigned*)(p + 2);
                float v0 = bflo(u0), v1 = bfhi(u0), v2_ = bflo(u1), v3_ = bfhi(u1);
#pragma unroll
                for (int dt = 0; dt < 3; ++dt) {
                    int r = rr - dt;
                    if (r >= 0 && r < 8) {
                        acc0[r] = fmaf(v0, wr[dt * 3],
                                  fmaf(v1, wr[dt * 3 + 1],
                                  fmaf(v2_, wr[dt * 3 + 2], acc0[r])));
                        acc1[r] = fmaf(v1, wr[dt * 3],
                                  fmaf(v2_, wr[dt * 3 + 1],
                                  fmaf(v3_, wr[dt * 3 + 2], acc1[r])));
                    }
                }
            }
        }
        float s = scl3[co], sh = shf3[co];
#pragma unroll
        for (int r = 0; r < 8; ++r) {
            float y0 = fmaxf(acc0[r] * s + sh, 0.f);
            float y1 = fmaxf(acc1[r] * s + sh, 0.f);
            x3out[(size_t)(b * T_ + t0 + r) * KP_ + co * 57 + j] =
                __float2bfloat16(fmaxf(y0, y1));
        }
    } else if (tid >= 627 && tid < 640) {
        __hip_bfloat16 z = __float2bfloat16(0.f);
#pragma unroll
        for (int r = 0; r < 8; ++r)
            x3out[(size_t)(b * T_ + t0 + r) * KP_ + tid] = z;
    }
}

// -------- W' = [wq;wk;wv] @ fc_w -> bf16 [144][640] (padded), b' fp32 --------
__global__ __launch_bounds__(256) void wprime_kernel(const float* __restrict__ fc_w,
        const float* __restrict__ fc_b, const float* __restrict__ wq,
        const float* __restrict__ wk, const float* __restrict__ wv,
        __hip_bfloat16* __restrict__ wp, float* __restrict__ bp) {
    int idx = blockIdx.x * 256 + threadIdx.x;
    if (idx < 144 * KP_) {
        int o = idx / KP_;
        int kk = idx % KP_;
        const float* Wrow = (o < 48) ? (wq + o * 88)
                          : (o < 96) ? (wk + (o - 48) * 88) : (wv + (o - 96) * 88);
        float s = 0.f;
        if (kk < 627)
            for (int i = 0; i < 88; ++i) s = fmaf(Wrow[i], fc_w[(size_t)i * 627 + kk], s);
        wp[idx] = __float2bfloat16(s);
    } else if (idx < 144 * KP_ + 144) {
        int o = idx - 144 * KP_;
        const float* Wrow = (o < 48) ? (wq + o * 88)
                          : (o < 96) ? (wk + (o - 48) * 88) : (wv + (o - 96) * 88);
        float s = 0.f;
        for (int i = 0; i < 88; ++i) s = fmaf(Wrow[i], fc_b[i], s);
        bp[o] = s;
    }
}

// -------- fused FC+QKV via MFMA bf16 (internally repeated x FC_REP) --------
__global__ __launch_bounds__(256) void fc_qkv_mfma_kernel(
        const __hip_bfloat16* __restrict__ X, const __hip_bfloat16* __restrict__ Wp,
        const float* __restrict__ bp, float* __restrict__ Q) {
    int tid = threadIdx.x;
    int lane = tid & 63;
    int gw = blockIdx.x * 4 + (tid >> 6);
    int mtile = gw / 3;
    int nthird = gw % 3;
    const short* Xs = (const short*)X;
    const short* Ws = (const short*)Wp;
    int klane = (lane >> 4) * 8;
    const short* xrow = Xs + (size_t)(mtile * 16 + (lane & 15)) * KP_ + klane;
    const short* wrow = Ws + (size_t)(nthird * 48 + (lane & 15)) * KP_ + klane;
#pragma unroll 1
    for (int rep = 0; rep < FC_REP; ++rep) {
        f32x4 acc0 = {0.f, 0.f, 0.f, 0.f}, acc1 = acc0, acc2 = acc0;
#pragma unroll 4
        for (int kt = 0; kt < 20; ++kt) {
            short8 a = *(const short8*)(xrow + kt * 32);
            short8 b0 = *(const short8*)(wrow + kt * 32);
            short8 b1 = *(const short8*)(wrow + 16 * KP_ + kt * 32);
            short8 b2 = *(const short8*)(wrow + 32 * KP_ + kt * 32);
            acc0 = __builtin_amdgcn_mfma_f32_16x16x32_bf16(a, b0, acc0, 0, 0, 0);
            acc1 = __builtin_amdgcn_mfma_f32_16x16x32_bf16(a, b1, acc1, 0, 0, 0);
            acc2 = __builtin_amdgcn_mfma_f32_16x16x32_bf16(a, b2, acc2, 0, 0, 0);
        }
        int r0 = mtile * 16 + (lane >> 4) * 4;
        int col = lane & 15;
        f32x4 accs[3] = {acc0, acc1, acc2};
#pragma unroll
        for (int nt = 0; nt < 3; ++nt) {
            int o = nthird * 48 + nt * 16 + col;
            float bias = bp[o];
#pragma unroll
            for (int rg = 0; rg < 4; ++rg)
                Q[(size_t)(r0 + rg) * 144 + o] = accs[nt][rg] + bias;
        }
        __syncthreads();   // keep reps ordered; prevents cross-rep CSE/hoist
    }
}

// ----- attention + LN + linear + sigmoid (internally repeated x ATTN_REP) -----
__global__ __launch_bounds__(128) void attn_ln_kernel(const float* __restrict__ Q,
        const float* __restrict__ rel, const float* __restrict__ lng,
        const float* __restrict__ lnb, const float* __restrict__ lw,
        const float* __restrict__ lb, float* __restrict__ fp,
        float* __restrict__ aout) {
    __shared__ float smem[6088];
    __shared__ float mus[TT_], rss[TT_];
    float* kvt = smem;               // 46 rows x 100
    float* relT = smem + 4600;       // 31 x 48
    int b = blockIdx.y;
    int t0 = blockIdx.x * TT_;
    int tid = threadIdx.x;
    int g = tid & 7;
    int tl = tid >> 3;
#pragma unroll 1
    for (int rep = 0; rep < ATTN_REP; ++rep) {
        for (int i = tid; i < 46 * 48; i += 128) {
            int row = i / 48, c2 = i % 48;
            int t = t0 - 15 + row;
            float2 v = {0.f, 0.f};
            if (t >= 0 && t < T_)
                v = *(const float2*)&Q[((size_t)b * T_ + t) * 144 + 48 + 2 * c2];
            *(float2*)&kvt[row * 100 + 2 * c2] = v;
        }
        for (int i = tid; i < 31 * 48; i += 128) {
            int kp = i / 48, j = i % 48;
            relT[i] = rel[j * 31 + kp];
        }
        const float* qg = &Q[((size_t)b * T_ + t0 + tl) * 144 + g * 6];
        float2 q01 = *(const float2*)qg;
        float2 q23 = *(const float2*)(qg + 2);
        float2 q45 = *(const float2*)(qg + 4);
        __syncthreads();
        float e[31];
        float emax = -1e30f;
#pragma unroll
        for (int kp = 0; kp < 31; ++kp) {
            const float* kr = &kvt[(tl + kp) * 100 + g * 6];
            const float* rr = &relT[kp * 48 + g * 6];
            float2 k01 = *(const float2*)kr;
            float2 k23 = *(const float2*)(kr + 2);
            float2 k45 = *(const float2*)(kr + 4);
            float2 r01 = *(const float2*)rr;
            float2 r23 = *(const float2*)(rr + 2);
            float2 r45 = *(const float2*)(rr + 4);
            float s = fmaf(q01.x, k01.x + r01.x,
                      fmaf(q01.y, k01.y + r01.y,
                      fmaf(q23.x, k23.x + r23.x,
                      fmaf(q23.y, k23.y + r23.y,
                      fmaf(q45.x, k45.x + r45.x,
                           q45.y * (k45.y + r45.y))))));
            e[kp] = s;
            emax = fmaxf(emax, s);
        }
        float sum = 0.f;
#pragma unroll
        for (int kp = 0; kp < 31; ++kp) { e[kp] = __expf(e[kp] - emax); sum += e[kp]; }
        float inv = 1.f / sum;
        float o0 = 0, o1 = 0, o2 = 0, o3 = 0, o4 = 0, o5 = 0;
#pragma unroll
        for (int kp = 0; kp < 31; ++kp) {
            float a = e[kp] * inv;
            e[kp] = a;
            const float* vr = &kvt[(tl + kp) * 100 + 48 + g * 6];
            float2 v01 = *(const float2*)vr;
            float2 v23 = *(const float2*)(vr + 2);
            float2 v45 = *(const float2*)(vr + 4);
            o0 = fmaf(a, v01.x, o0); o1 = fmaf(a, v01.y, o1);
            o2 = fmaf(a, v23.x, o2); o3 = fmaf(a, v23.y, o3);
            o4 = fmaf(a, v45.x, o4); o5 = fmaf(a, v45.y, o5);
        }
        __syncthreads();
        float* abuf = smem;              // 128 x 31 = 3968
        float* xr = smem + 3968;         // 16 x 48 = 768
#pragma unroll
        for (int kp = 0; kp < 31; ++kp) abuf[tid * 31 + kp] = e[kp];
        {
            float* xp = &xr[tl * 48 + g * 6];
            xp[0] = o0; xp[1] = o1; xp[2] = o2; xp[3] = o3; xp[4] = o4; xp[5] = o5;
        }
        __syncthreads();
        size_t base = ((size_t)b * T_ + t0) * 248;
        for (int i = tid; i < 992; i += 128) {
            float4 v = *(const float4*)&abuf[4 * i];
            *(float4*)&aout[base + 4 * i] = v;
        }
        if (tid < TT_) {
            const float* row = &xr[tid * 48];
            float s = 0.f;
            for (int c = 0; c < 48; ++c) s += row[c];
            float mu = s * (1.f / 48.f);
            float v2 = 0.f;
            for (int c = 0; c < 48; ++c) { float d = row[c] - mu; v2 = fmaf(d, d, v2); }
            mus[tid] = mu;
            rss[tid] = rsqrtf(v2 * (1.f / 48.f) + LN_EPS);
        }
        __syncthreads();
        for (int i = tid; i < TT_ * 48; i += 128) {
            int r = i / 48, c = i % 48;
            xr[i] = fmaf((xr[i] - mus[r]) * rss[r], lng[c], lnb[c]);
        }
        __syncthreads();
        size_t obase = ((size_t)b * T_ + t0) * 88;
        for (int k = 0; k < 11; ++k) {
            int cid = k * 128 + tid;
            int o = cid % 88, r = cid / 88;
            const float* xp = &xr[r * 48];
            const float* wpp = &lw[o * 48];
            float s = lb[o];
#pragma unroll
            for (int c = 0; c < 48; c += 4) {
                float4 xv = *(const float4*)&xp[c];
                float4 wv = *(const float4*)&wpp[c];
                s = fmaf(xv.x, wv.x, s);
                s = fmaf(xv.y, wv.y, s);
                s = fmaf(xv.z, wv.z, s);
                s = fmaf(xv.w, wv.w, s);
            }
            fp[obase + cid] = 1.f / (1.f + __expf(-s));
        }
        __syncthreads();   // drain before re-staging kvt next rep
    }
}

extern "C" void kernel_launch(void* const* d_in, const int* in_sizes, int n_in,
                              void* d_out, int out_size, void* d_ws, size_t ws_size,
                              hipStream_t stream) {
    const float* spec = (const float*)d_in[0];
    const float* c1_w = (const float*)d_in[1];
    const float* c1_b = (const float*)d_in[2];
    const float* bn1_g = (const float*)d_in[3];
    const float* bn1_b = (const float*)d_in[4];
    const float* bn1_m = (const float*)d_in[5];
    const float* bn1_v = (const float*)d_in[6];
    const float* c2_w = (const float*)d_in[7];
    const float* c2_b = (const float*)d_in[8];
    const float* bn2_g = (const float*)d_in[9];
    const float* bn2_b = (const float*)d_in[10];
    const float* bn2_m = (const float*)d_in[11];
    const float* bn2_v = (const float*)d_in[12];
    const float* c3_w = (const float*)d_in[13];
    const float* c3_b = (const float*)d_in[14];
    const float* bn3_g = (const float*)d_in[15];
    const float* bn3_b = (const float*)d_in[16];
    const float* bn3_m = (const float*)d_in[17];
    const float* bn3_v = (const float*)d_in[18];
    const float* fc_w = (const float*)d_in[19];
    const float* fc_b = (const float*)d_in[20];
    const float* wq = (const float*)d_in[21];
    const float* wk = (const float*)d_in[22];
    const float* wv = (const float*)d_in[23];
    const float* rel = (const float*)d_in[24];
    const float* ln_g = (const float*)d_in[25];
    const float* ln_b = (const float*)d_in[26];
    const float* lin_w = (const float*)d_in[27];
    const float* lin_b = (const float*)d_in[28];

    float* ws = (float*)d_ws;
    __hip_bfloat16* x3bf = (__hip_bfloat16*)ws;                 // 13.1M bf16
    __hip_bfloat16* wp_bf = (__hip_bfloat16*)(ws + 19000000);
    float* bp = ws + 19100000;
    float* Qb = ws + 23449600;

    float* frame_pred = (float*)d_out;
    float* a_out = frame_pred + (size_t)B_ * T_ * OF_;

    wprime_kernel<<<cdiv(144 * KP_ + 144, 256), 256, 0, stream>>>(fc_w, fc_b, wq, wk, wv,
                                                                  wp_bf, bp);
    conv123_kernel<<<dim3(T_ / TS_, B_), 640, 0, stream>>>(
        spec, c1_w, c1_b, bn1_g, bn1_b, bn1_m, bn1_v,
        c2_w, c2_b, bn2_g, bn2_b, bn2_m, bn2_v,
        c3_w, c3_b, bn3_g, bn3_b, bn3_m, bn3_v, x3bf);
    fc_qkv_mfma_kernel<<<960, 256, 0, stream>>>(x3bf, wp_bf, bp, Qb);
    attn_ln_kernel<<<dim3(T_ / TT_, B_), 128, 0, stream>>>(Qb, rel, ln_g, ln_b, lin_w,
                                                           lin_b, frame_pred, a_out);
}

// Round 15
// 326.987 us; speedup vs baseline: 1.6121x; 1.6121x over previous
//
#include <hip/hip_runtime.h>
#include <hip/hip_bf16.h>
#include <math.h>

#define B_    8
#define T_    2560
#define F_    229
#define C1_   5
#define C2_   11
#define W1_   114
#define W2_   57
#define KP_   640
#define OF_   88
#define MC_   48
#define G_    8
#define DH_   6
#define K_    31
#define PAD_  15
#define BN_EPS 1e-5f
#define LN_EPS 1e-5f
#define TS_   8
#define TT_   16    // attn t-tile

typedef __attribute__((ext_vector_type(8))) short short8;
typedef __attribute__((ext_vector_type(4))) float f32x4;

static inline int cdiv(int a, int b) { return (a + b - 1) / b; }

__device__ inline float bflo(unsigned u) { return __uint_as_float(u << 16); }
__device__ inline float bfhi(unsigned u) { return __uint_as_float(u & 0xffff0000u); }

// ---- fused conv1+conv2+pool+conv3+pool: spec (B,T,229) -> x3bf [bt][640] ----
__global__ __launch_bounds__(640, 8) void conv123_kernel(
        const float* __restrict__ spec,
        const float* __restrict__ c1w, const float* __restrict__ c1b,
        const float* __restrict__ g1, const float* __restrict__ b1,
        const float* __restrict__ m1, const float* __restrict__ v1,
        const float* __restrict__ c2w, const float* __restrict__ c2b,
        const float* __restrict__ g2, const float* __restrict__ b2,
        const float* __restrict__ m2, const float* __restrict__ v2,
        const float* __restrict__ c3w, const float* __restrict__ c3b,
        const float* __restrict__ g3, const float* __restrict__ b3,
        const float* __restrict__ m3, const float* __restrict__ v3,
        __hip_bfloat16* __restrict__ x3out) {
    __shared__ ushort x1t[12 * 5 * 232];     // 27,840 B bf16 (col = f+1)
    __shared__ float specx2[14 * 232];       // 12,992 B: spec tile, then x2p bf16 tile
    __shared__ float w1s[45], w2s[225], w3s[495];
    __shared__ float scl1[5], shf1[5], scl2[5], shf2[5], scl3[11], shf3[11];
    int t0 = blockIdx.x * TS_;
    int b = blockIdx.y;
    int tid = threadIdx.x;

    if (tid < 45) w1s[tid] = c1w[tid];
    for (int i = tid; i < 225; i += 640) w2s[i] = c2w[i];
    for (int i = tid; i < 495; i += 640) w3s[i] = c3w[i];
    if (tid < 5) {
        float s = g1[tid] * rsqrtf(v1[tid] + BN_EPS);
        scl1[tid] = s;
        shf1[tid] = (c1b[tid] - m1[tid]) * s + b1[tid];
    }
    if (tid >= 64 && tid < 69) {
        int c = tid - 64;
        float s = g2[c] * rsqrtf(v2[c] + BN_EPS);
        scl2[c] = s;
        shf2[c] = (c2b[c] - m2[c]) * s + b2[c];
    }
    if (tid >= 128 && tid < 139) {
        int c = tid - 128;
        float s = g3[c] * rsqrtf(v3[c] + BN_EPS);
        scl3[c] = s;
        shf3[c] = (c3b[c] - m3[c]) * s + b3[c];
    }
    {
        const float* sb = spec + (size_t)b * T_ * F_;
        for (int i = tid; i < 14 * 232; i += 640) {
            int col = i % 232;
            int rr = i / 232;
            int t = t0 - 3 + rr;
            int f = col - 1;
            float v = 0.f;
            if (t >= 0 && t < T_ && f >= 0 && f < F_) v = sb[(size_t)t * F_ + f];
            specx2[i] = v;
        }
    }
    __syncthreads();

    // ---- phase 1: conv1+bn+relu -> x1t rows t0-2..t0+9 (bf16) ----
    for (int i = tid; i < 12 * 229; i += 640) {
        int f = i % 229;
        int rr = i / 229;
        int t = t0 - 2 + rr;
        float y[5];
        if (t >= 0 && t < T_) {
            float tp[9];
#pragma unroll
            for (int dt = 0; dt < 3; ++dt) {
                const float* row = &specx2[(rr + dt) * 232 + f];
                tp[dt * 3 + 0] = row[0];
                tp[dt * 3 + 1] = row[1];
                tp[dt * 3 + 2] = row[2];
            }
#pragma unroll
            for (int co = 0; co < 5; ++co) {
                float acc = 0.f;
#pragma unroll
                for (int k = 0; k < 9; ++k) acc = fmaf(tp[k], w1s[co * 9 + k], acc);
                y[co] = fmaxf(fmaf(acc, scl1[co], shf1[co]), 0.f);
            }
        } else {
#pragma unroll
            for (int co = 0; co < 5; ++co) y[co] = 0.f;
        }
#pragma unroll
        for (int co = 0; co < 5; ++co) {
            __hip_bfloat16 h = __float2bfloat16(y[co]);
            x1t[(rr * 5 + co) * 232 + 1 + f] = *(ushort*)&h;
        }
    }
    for (int i = tid; i < 180; i += 640) {
        int c = i % 3;
        int col = (c == 0) ? 0 : 229 + c;
        int ci = (i / 3) % 5;
        int rr = i / 15;
        x1t[(rr * 5 + ci) * 232 + col] = 0;
    }
    __syncthreads();

    // ---- phase 2: conv2+bn+relu+pool -> x2pt (bf16, unions with spec tile) ----
    ushort* x2pt = (ushort*)specx2;
    if (tid < 570) {
        int co = tid / 114;
        int j = tid % 114;
        float acc0[10], acc1[10];
#pragma unroll
        for (int r = 0; r < 10; ++r) { acc0[r] = 0.f; acc1[r] = 0.f; }
#pragma unroll
        for (int ci = 0; ci < 5; ++ci) {
            float wr[9];
#pragma unroll
            for (int k = 0; k < 9; ++k) wr[k] = w2s[(co * 5 + ci) * 9 + k];
#pragma unroll
            for (int rr = 0; rr < 12; ++rr) {
                const ushort* p = &x1t[(rr * 5 + ci) * 232 + 2 * j];
                unsigned u0 = *(const unsigned*)p;
                unsigned u1 = *(const unsigned*)(p + 2);
                float v0 = bflo(u0), v1 = bfhi(u0), v2_ = bflo(u1), v3_ = bfhi(u1);
#pragma unroll
                for (int dt = 0; dt < 3; ++dt) {
                    int r = rr - dt;
                    if (r >= 0 && r < 10) {
                        acc0[r] = fmaf(v0, wr[dt * 3],
                                  fmaf(v1, wr[dt * 3 + 1],
                                  fmaf(v2_, wr[dt * 3 + 2], acc0[r])));
                        acc1[r] = fmaf(v1, wr[dt * 3],
                                  fmaf(v2_, wr[dt * 3 + 1],
                                  fmaf(v3_, wr[dt * 3 + 2], acc1[r])));
                    }
                }
            }
        }
        float s = scl2[co], sh = shf2[co];
        float yv[10];
#pragma unroll
        for (int r = 0; r < 10; ++r) {
            int t = t0 - 1 + r;
            float y = fmaxf(fmaxf(acc0[r] * s + sh, 0.f), fmaxf(acc1[r] * s + sh, 0.f));
            yv[r] = (t < 0 || t >= T_) ? 0.f : y;
        }
        __syncthreads();
#pragma unroll
        for (int r = 0; r < 10; ++r) {
            __hip_bfloat16 h = __float2bfloat16(yv[r]);
            x2pt[(r * 5 + co) * 120 + 1 + j] = *(ushort*)&h;
        }
    } else {
        __syncthreads();
        for (int i = tid - 570; i < 300; i += 70) {
            int cc = i % 6;
            int col = (cc == 0) ? 0 : 114 + cc;
            int ci = (i / 6) % 5;
            int r = i / 30;
            x2pt[(r * 5 + ci) * 120 + col] = 0;
        }
    }
    __syncthreads();

    // ---- phase 3: conv3+bn+relu+pool -> x3out bf16 [bt][640] ----
    if (tid < 627) {
        int co = tid / 57;
        int j = tid % 57;
        float acc0[8], acc1[8];
#pragma unroll
        for (int r = 0; r < 8; ++r) { acc0[r] = 0.f; acc1[r] = 0.f; }
#pragma unroll
        for (int ci = 0; ci < 5; ++ci) {
            float wr[9];
#pragma unroll
            for (int k = 0; k < 9; ++k) wr[k] = w3s[(co * 5 + ci) * 9 + k];
#pragma unroll
            for (int rr = 0; rr < 10; ++rr) {
                const ushort* p = &x2pt[(rr * 5 + ci) * 120 + 2 * j];
                unsigned u0 = *(const unsigned*)p;
                unsigned u1 = *(const unsigned*)(p + 2);
                float v0 = bflo(u0), v1 = bfhi(u0), v2_ = bflo(u1), v3_ = bfhi(u1);
#pragma unroll
                for (int dt = 0; dt < 3; ++dt) {
                    int r = rr - dt;
                    if (r >= 0 && r < 8) {
                        acc0[r] = fmaf(v0, wr[dt * 3],
                                  fmaf(v1, wr[dt * 3 + 1],
                                  fmaf(v2_, wr[dt * 3 + 2], acc0[r])));
                        acc1[r] = fmaf(v1, wr[dt * 3],
                                  fmaf(v2_, wr[dt * 3 + 1],
                                  fmaf(v3_, wr[dt * 3 + 2], acc1[r])));
                    }
                }
            }
        }
        float s = scl3[co], sh = shf3[co];
#pragma unroll
        for (int r = 0; r < 8; ++r) {
            float y0 = fmaxf(acc0[r] * s + sh, 0.f);
            float y1 = fmaxf(acc1[r] * s + sh, 0.f);
            x3out[(size_t)(b * T_ + t0 + r) * KP_ + co * 57 + j] =
                __float2bfloat16(fmaxf(y0, y1));
        }
    } else if (tid >= 627 && tid < 640) {
        __hip_bfloat16 z = __float2bfloat16(0.f);
#pragma unroll
        for (int r = 0; r < 8; ++r)
            x3out[(size_t)(b * T_ + t0 + r) * KP_ + tid] = z;
    }
}

// -------- W' = [wq;wk;wv] @ fc_w -> bf16 [144][640] (padded), b' fp32 --------
__global__ __launch_bounds__(256) void wprime_kernel(const float* __restrict__ fc_w,
        const float* __restrict__ fc_b, const float* __restrict__ wq,
        const float* __restrict__ wk, const float* __restrict__ wv,
        __hip_bfloat16* __restrict__ wp, float* __restrict__ bp) {
    int idx = blockIdx.x * 256 + threadIdx.x;
    if (idx < 144 * KP_) {
        int o = idx / KP_;
        int kk = idx % KP_;
        const float* Wrow = (o < 48) ? (wq + o * 88)
                          : (o < 96) ? (wk + (o - 48) * 88) : (wv + (o - 96) * 88);
        float s = 0.f;
        if (kk < 627)
            for (int i = 0; i < 88; ++i) s = fmaf(Wrow[i], fc_w[(size_t)i * 627 + kk], s);
        wp[idx] = __float2bfloat16(s);
    } else if (idx < 144 * KP_ + 144) {
        int o = idx - 144 * KP_;
        const float* Wrow = (o < 48) ? (wq + o * 88)
                          : (o < 96) ? (wk + (o - 48) * 88) : (wv + (o - 96) * 88);
        float s = 0.f;
        for (int i = 0; i < 88; ++i) s = fmaf(Wrow[i], fc_b[i], s);
        bp[o] = s;
    }
}

// -------- fused FC+QKV via MFMA bf16: Q[bt][144] = X[bt][640] @ W'^T + b' --------
__global__ __launch_bounds__(256) void fc_qkv_mfma_kernel(
        const __hip_bfloat16* __restrict__ X, const __hip_bfloat16* __restrict__ Wp,
        const float* __restrict__ bp, float* __restrict__ Q) {
    int tid = threadIdx.x;
    int lane = tid & 63;
    int gw = blockIdx.x * 4 + (tid >> 6);
    int mtile = gw / 3;
    int nthird = gw % 3;
    const short* Xs = (const short*)X;
    const short* Ws = (const short*)Wp;
    int klane = (lane >> 4) * 8;
    const short* xrow = Xs + (size_t)(mtile * 16 + (lane & 15)) * KP_ + klane;
    const short* wrow = Ws + (size_t)(nthird * 48 + (lane & 15)) * KP_ + klane;
    f32x4 acc0 = {0.f, 0.f, 0.f, 0.f}, acc1 = acc0, acc2 = acc0;
#pragma unroll 4
    for (int kt = 0; kt < 20; ++kt) {
        short8 a = *(const short8*)(xrow + kt * 32);
        short8 b0 = *(const short8*)(wrow + kt * 32);
        short8 b1 = *(const short8*)(wrow + 16 * KP_ + kt * 32);
        short8 b2 = *(const short8*)(wrow + 32 * KP_ + kt * 32);
        acc0 = __builtin_amdgcn_mfma_f32_16x16x32_bf16(a, b0, acc0, 0, 0, 0);
        acc1 = __builtin_amdgcn_mfma_f32_16x16x32_bf16(a, b1, acc1, 0, 0, 0);
        acc2 = __builtin_amdgcn_mfma_f32_16x16x32_bf16(a, b2, acc2, 0, 0, 0);
    }
    int r0 = mtile * 16 + (lane >> 4) * 4;
    int col = lane & 15;
    f32x4 accs[3] = {acc0, acc1, acc2};
#pragma unroll
    for (int nt = 0; nt < 3; ++nt) {
        int o = nthird * 48 + nt * 16 + col;
        float bias = bp[o];
#pragma unroll
        for (int rg = 0; rg < 4; ++rg)
            Q[(size_t)(r0 + rg) * 144 + o] = accs[nt][rg] + bias;
    }
}

// ----- attention + LN + linear + sigmoid; split-kp via shfl_xor pairs -----
// 256 thr / 16-t tile. Pair (tid, tid^1) shares one (t,g); h=tid&1 takes taps
// kp = 2*i+h. Combine max/sum/o via __shfl_xor (same wave, register-only).
__global__ __launch_bounds__(256) void attn_ln_kernel(const float* __restrict__ Q,
        const float* __restrict__ rel, const float* __restrict__ lng,
        const float* __restrict__ lnb, const float* __restrict__ lw,
        const float* __restrict__ lb, float* __restrict__ fp,
        float* __restrict__ aout) {
    __shared__ float smem[6088];     // kvt[0,4600) relT[4600,6088)
                                     // reuse after drain: abuf[0,3968) xr[3968,4736)
    __shared__ float mus[TT_], rss[TT_];
    float* kvt = smem;               // 46 rows x 100 (k: 0..47, v: 48..95)
    float* relT = smem + 4600;       // [kp][j]
    int b = blockIdx.y;
    int t0 = blockIdx.x * TT_;
    int tid = threadIdx.x;
    int h = tid & 1;                 // tap-parity half
    int p = tid >> 1;                // pair id 0..127
    int g = p & 7;
    int tl = p >> 3;                 // 0..15
    for (int i = tid; i < 46 * 48; i += 256) {
        int row = i / 48, c2 = i % 48;
        int t = t0 - 15 + row;
        float2 v = {0.f, 0.f};
        if (t >= 0 && t < T_)
            v = *(const float2*)&Q[((size_t)b * T_ + t) * 144 + 48 + 2 * c2];
        *(float2*)&kvt[row * 100 + 2 * c2] = v;
    }
    for (int i = tid; i < 31 * 48; i += 256) {
        int kp = i / 48, j = i % 48;
        relT[i] = rel[j * 31 + kp];
    }
    const float* qg = &Q[((size_t)b * T_ + t0 + tl) * 144 + g * 6];
    float2 q01 = *(const float2*)qg;
    float2 q23 = *(const float2*)(qg + 2);
    float2 q45 = *(const float2*)(qg + 4);
    __syncthreads();
    float e[16];
    float m_h = -1e30f;
#pragma unroll
    for (int i = 0; i < 16; ++i) {
        int kp = 2 * i + h;
        if (kp < 31) {
            const float* kr = &kvt[(tl + kp) * 100 + g * 6];
            const float* rr = &relT[kp * 48 + g * 6];
            float2 k01 = *(const float2*)kr;
            float2 k23 = *(const float2*)(kr + 2);
            float2 k45 = *(const float2*)(kr + 4);
            float2 r01 = *(const float2*)rr;
            float2 r23 = *(const float2*)(rr + 2);
            float2 r45 = *(const float2*)(rr + 4);
            float s = fmaf(q01.x, k01.x + r01.x,
                      fmaf(q01.y, k01.y + r01.y,
                      fmaf(q23.x, k23.x + r23.x,
                      fmaf(q23.y, k23.y + r23.y,
                      fmaf(q45.x, k45.x + r45.x,
                           q45.y * (k45.y + r45.y))))));
            e[i] = s;
            m_h = fmaxf(m_h, s);
        }
    }
    float M = fmaxf(m_h, __shfl_xor(m_h, 1));
    float s_h = 0.f;
    float o0 = 0, o1 = 0, o2 = 0, o3 = 0, o4 = 0, o5 = 0;
#pragma unroll
    for (int i = 0; i < 16; ++i) {
        int kp = 2 * i + h;
        if (kp < 31) {
            float a = __expf(e[i] - M);
            e[i] = a;
            s_h += a;
            const float* vr = &kvt[(tl + kp) * 100 + 48 + g * 6];
            float2 v01 = *(const float2*)vr;
            float2 v23 = *(const float2*)(vr + 2);
            float2 v45 = *(const float2*)(vr + 4);
            o0 = fmaf(a, v01.x, o0); o1 = fmaf(a, v01.y, o1);
            o2 = fmaf(a, v23.x, o2); o3 = fmaf(a, v23.y, o3);
            o4 = fmaf(a, v45.x, o4); o5 = fmaf(a, v45.y, o5);
        }
    }
    float sum = s_h + __shfl_xor(s_h, 1);
    float inv = 1.f / sum;
    float t0s = o0 + __shfl_xor(o0, 1);
    float t1s = o1 + __shfl_xor(o1, 1);
    float t2s = o2 + __shfl_xor(o2, 1);
    float t3s = o3 + __shfl_xor(o3, 1);
    float t4s = o4 + __shfl_xor(o4, 1);
    float t5s = o5 + __shfl_xor(o5, 1);
    __syncthreads();                 // all kvt/relT reads complete; reuse LDS
    float* abuf = smem;              // [t][g][31] = 3968 floats
    float* xr = smem + 3968;         // 16 x 48
#pragma unroll
    for (int i = 0; i < 16; ++i) {
        int kp = 2 * i + h;
        if (kp < 31) abuf[p * 31 + kp] = e[i] * inv;
    }
    if (h == 0) {
        float* xp = &xr[tl * 48 + g * 6];
        xp[0] = t0s * inv; xp[1] = t1s * inv; xp[2] = t2s * inv;
        xp[3] = t3s * inv; xp[4] = t4s * inv; xp[5] = t5s * inv;
    }
    __syncthreads();
    size_t base = ((size_t)b * T_ + t0) * 248;
    for (int i = tid; i < 992; i += 256) {
        float4 v = *(const float4*)&abuf[4 * i];
        *(float4*)&aout[base + 4 * i] = v;
    }
    if (tid < TT_) {
        const float* row = &xr[tid * 48];
        float s = 0.f;
        for (int c = 0; c < 48; ++c) s += row[c];
        float mu = s * (1.f / 48.f);
        float v2 = 0.f;
        for (int c = 0; c < 48; ++c) { float d = row[c] - mu; v2 = fmaf(d, d, v2); }
        mus[tid] = mu;
        rss[tid] = rsqrtf(v2 * (1.f / 48.f) + LN_EPS);
    }
    __syncthreads();
    for (int i = tid; i < TT_ * 48; i += 256) {
        int r = i / 48, c = i % 48;
        xr[i] = fmaf((xr[i] - mus[r]) * rss[r], lng[c], lnb[c]);
    }
    __syncthreads();
    size_t obase = ((size_t)b * T_ + t0) * 88;
    for (int i = tid; i < TT_ * 88; i += 256) {
        int o = i % 88, r = i / 88;
        const float* xp = &xr[r * 48];
        const float* wpp = &lw[o * 48];
        float s = lb[o];
#pragma unroll
        for (int c = 0; c < 48; c += 4) {
            float4 xv = *(const float4*)&xp[c];
            float4 wv = *(const float4*)&wpp[c];
            s = fmaf(xv.x, wv.x, s);
            s = fmaf(xv.y, wv.y, s);
            s = fmaf(xv.z, wv.z, s);
            s = fmaf(xv.w, wv.w, s);
        }
        fp[obase + i] = 1.f / (1.f + __expf(-s));
    }
}

extern "C" void kernel_launch(void* const* d_in, const int* in_sizes, int n_in,
                              void* d_out, int out_size, void* d_ws, size_t ws_size,
                              hipStream_t stream) {
    const float* spec = (const float*)d_in[0];
    const float* c1_w = (const float*)d_in[1];
    const float* c1_b = (const float*)d_in[2];
    const float* bn1_g = (const float*)d_in[3];
    const float* bn1_b = (const float*)d_in[4];
    const float* bn1_m = (const float*)d_in[5];
    const float* bn1_v = (const float*)d_in[6];
    const float* c2_w = (const float*)d_in[7];
    const float* c2_b = (const float*)d_in[8];
    const float* bn2_g = (const float*)d_in[9];
    const float* bn2_b = (const float*)d_in[10];
    const float* bn2_m = (const float*)d_in[11];
    const float* bn2_v = (const float*)d_in[12];
    const float* c3_w = (const float*)d_in[13];
    const float* c3_b = (const float*)d_in[14];
    const float* bn3_g = (const float*)d_in[15];
    const float* bn3_b = (const float*)d_in[16];
    const float* bn3_m = (const float*)d_in[17];
    const float* bn3_v = (const float*)d_in[18];
    const float* fc_w = (const float*)d_in[19];
    const float* fc_b = (const float*)d_in[20];
    const float* wq = (const float*)d_in[21];
    const float* wk = (const float*)d_in[22];
    const float* wv = (const float*)d_in[23];
    const float* rel = (const float*)d_in[24];
    const float* ln_g = (const float*)d_in[25];
    const float* ln_b = (const float*)d_in[26];
    const float* lin_w = (const float*)d_in[27];
    const float* lin_b = (const float*)d_in[28];

    float* ws = (float*)d_ws;
    __hip_bfloat16* x3bf = (__hip_bfloat16*)ws;                 // 13.1M bf16
    __hip_bfloat16* wp_bf = (__hip_bfloat16*)(ws + 19000000);
    float* bp = ws + 19100000;
    float* Qb = ws + 23449600;

    float* frame_pred = (float*)d_out;
    float* a_out = frame_pred + (size_t)B_ * T_ * OF_;

    wprime_kernel<<<cdiv(144 * KP_ + 144, 256), 256, 0, stream>>>(fc_w, fc_b, wq, wk, wv,
                                                                  wp_bf, bp);
    conv123_kernel<<<dim3(T_ / TS_, B_), 640, 0, stream>>>(
        spec, c1_w, c1_b, bn1_g, bn1_b, bn1_m, bn1_v,
        c2_w, c2_b, bn2_g, bn2_b, bn2_m, bn2_v,
        c3_w, c3_b, bn3_g, bn3_b, bn3_m, bn3_v, x3bf);
    fc_qkv_mfma_kernel<<<960, 256, 0, stream>>>(x3bf, wp_bf, bp, Qb);
    attn_ln_kernel<<<dim3(T_ / TT_, B_), 256, 0, stream>>>(Qb, rel, ln_g, ln_b, lin_w,
                                                           lin_b, frame_pred, a_out);
}